// Round 1
// baseline (267.014 us; speedup 1.0000x reference)
//
#include <hip/hip_runtime.h>

#define SDIM 4096
#define HDIM 256
#define WIN 128
#define NROW 16384  // B*S

// ---------------- Kernel 1: QKV projection (fp32, VALU) ----------------
// grid 512, block 256. Each block: 32 rows of x (LDS), 3 matrices,
// thread tile = 8 rows x 4 cols.
__global__ __launch_bounds__(256) void qkv_proj(
    const float* __restrict__ x,
    const float* __restrict__ Wq, const float* __restrict__ bq,
    const float* __restrict__ Wk, const float* __restrict__ bk,
    const float* __restrict__ Wv, const float* __restrict__ bv,
    float* __restrict__ Q, float* __restrict__ K, float* __restrict__ V) {
  __shared__ float xs[32][HDIM + 4];
  const int tid = threadIdx.x;
  const size_t rb = (size_t)blockIdx.x * 32;
#pragma unroll
  for (int i = 0; i < 8; ++i) {
    int id = i * 256 + tid;
    int r = id >> 6, c4 = (id & 63) << 2;
    *(float4*)&xs[r][c4] = *(const float4*)(x + (rb + r) * HDIM + c4);
  }
  __syncthreads();
  const int td = tid & 63, tr = tid >> 6;
  const float* Wm[3] = {Wq, Wk, Wv};
  const float* bm[3] = {bq, bk, bv};
  float* Om[3] = {Q, K, V};
#pragma unroll
  for (int m = 0; m < 3; ++m) {
    const float* __restrict__ W = Wm[m];
    float acc[8][4];
#pragma unroll
    for (int r = 0; r < 8; ++r)
#pragma unroll
      for (int c = 0; c < 4; ++c) acc[r][c] = 0.f;
#pragma unroll 2
    for (int h = 0; h < HDIM; h += 4) {
      float4 w0 = *(const float4*)(W + (size_t)(h + 0) * HDIM + 4 * td);
      float4 w1 = *(const float4*)(W + (size_t)(h + 1) * HDIM + 4 * td);
      float4 w2 = *(const float4*)(W + (size_t)(h + 2) * HDIM + 4 * td);
      float4 w3 = *(const float4*)(W + (size_t)(h + 3) * HDIM + 4 * td);
#pragma unroll
      for (int r = 0; r < 8; ++r) {
        float4 xv = *(float4*)&xs[8 * tr + r][h];
        acc[r][0] += xv.x * w0.x + xv.y * w1.x + xv.z * w2.x + xv.w * w3.x;
        acc[r][1] += xv.x * w0.y + xv.y * w1.y + xv.z * w2.y + xv.w * w3.y;
        acc[r][2] += xv.x * w0.z + xv.y * w1.z + xv.z * w2.z + xv.w * w3.z;
        acc[r][3] += xv.x * w0.w + xv.y * w1.w + xv.z * w2.w + xv.w * w3.w;
      }
    }
    float4 bias = *(const float4*)(bm[m] + 4 * td);
    float* __restrict__ O = Om[m];
#pragma unroll
    for (int r = 0; r < 8; ++r) {
      float4 o = make_float4(acc[r][0] + bias.x, acc[r][1] + bias.y,
                             acc[r][2] + bias.z, acc[r][3] + bias.w);
      *(float4*)(O + (rb + 8 * tr + r) * HDIM + 4 * td) = o;
    }
  }
}

// ---------------- Kernel 2: banded attention with online softmax -------
// grid 512 (=B*(S/32)), block 256. QBLK=32, TCHUNK=32, 9 chunks covering
// [s0-128, s0+160). K and V time-share one LDS buffer. Partial column
// sums (context summed over the 32 q-rows) written per block.
__global__ __launch_bounds__(256) void local_attn(
    const float* __restrict__ Q, const float* __restrict__ K,
    const float* __restrict__ V, float* __restrict__ partial) {
  __shared__ float qs[32][HDIM + 4];
  __shared__ float kv[32][HDIM + 4];
  __shared__ float sc[32][36];
  __shared__ float mrow[32], lrow[32], srow[32];
  __shared__ float pbuf[4][HDIM];
  const int tid = threadIdx.x;
  const int blk = blockIdx.x;
  const int b = blk >> 7;
  const int s0 = (blk & 127) << 5;
  const float* Qb = Q + ((size_t)b * SDIM + s0) * HDIM;
  const float* Kb = K + (size_t)b * SDIM * HDIM;
  const float* Vb = V + (size_t)b * SDIM * HDIM;
#pragma unroll
  for (int i = 0; i < 8; ++i) {
    int id = i * 256 + tid;
    int r = id >> 6, c4 = (id & 63) << 2;
    *(float4*)&qs[r][c4] = *(const float4*)(Qb + (size_t)r * HDIM + c4);
  }
  if (tid < 32) { mrow[tid] = -1e30f; lrow[tid] = 0.f; }
  float acc[8][4];
#pragma unroll
  for (int r = 0; r < 8; ++r)
#pragma unroll
    for (int c = 0; c < 4; ++c) acc[r][c] = 0.f;
  const int td = tid & 63, tr = tid >> 6;
  const int tq = tid >> 4, tt = tid & 15;
  const int rr = tid >> 3, jj = tid & 7;
  __syncthreads();
  for (int cidx = 0; cidx < 9; ++cidx) {
    const int t0 = s0 - WIN + cidx * 32;
    if (t0 + 32 <= 0 || t0 >= SDIM) continue;  // uniform skip
    // ---- K chunk -> LDS (guarded) ----
#pragma unroll
    for (int i = 0; i < 8; ++i) {
      int id = i * 256 + tid;
      int r = id >> 6, c4 = (id & 63) << 2;
      int t = t0 + r;
      float4 kx = make_float4(0.f, 0.f, 0.f, 0.f);
      if (t >= 0 && t < SDIM) kx = *(const float4*)(Kb + (size_t)t * HDIM + c4);
      *(float4*)&kv[r][c4] = kx;
    }
    __syncthreads();
    // ---- scores: thread tile rows {tq, tq+16} x cols {tt, tt+16} ----
    float s00 = 0.f, s01 = 0.f, s10 = 0.f, s11 = 0.f;
#pragma unroll 2
    for (int h = 0; h < HDIM; h += 4) {
      float4 q0 = *(float4*)&qs[tq][h];
      float4 q1 = *(float4*)&qs[tq + 16][h];
      float4 k0 = *(float4*)&kv[tt][h];
      float4 k1 = *(float4*)&kv[tt + 16][h];
      s00 += q0.x * k0.x + q0.y * k0.y + q0.z * k0.z + q0.w * k0.w;
      s01 += q0.x * k1.x + q0.y * k1.y + q0.z * k1.z + q0.w * k1.w;
      s10 += q1.x * k0.x + q1.y * k0.y + q1.z * k0.z + q1.w * k0.w;
      s11 += q1.x * k1.x + q1.y * k1.y + q1.z * k1.z + q1.w * k1.w;
    }
    {
      const float rs = 0.0625f;  // 1/sqrt(256)
      int rows[2] = {tq, tq + 16};
      int cols[2] = {tt, tt + 16};
      float vals[2][2] = {{s00, s01}, {s10, s11}};
#pragma unroll
      for (int i = 0; i < 2; ++i)
#pragma unroll
        for (int j = 0; j < 2; ++j) {
          int r = rows[i];
          int t = t0 + cols[j];
          int s = s0 + r;
          bool ok = (t >= 0) && (t < SDIM) && (t >= s - WIN) && (t <= s + WIN);
          sc[r][cols[j]] = ok ? vals[i][j] * rs : -1e30f;
        }
    }
    __syncthreads();
    // ---- online softmax update (8 lanes per row, same wave) ----
    float4 pv = *(float4*)&sc[rr][4 * jj];
    float mc = fmaxf(fmaxf(pv.x, pv.y), fmaxf(pv.z, pv.w));
    mc = fmaxf(mc, __shfl_xor(mc, 1));
    mc = fmaxf(mc, __shfl_xor(mc, 2));
    mc = fmaxf(mc, __shfl_xor(mc, 4));
    float mold = mrow[rr];
    float mnew = fmaxf(mold, mc);
    float4 p;
    p.x = (pv.x > -1e29f) ? __expf(pv.x - mnew) : 0.f;
    p.y = (pv.y > -1e29f) ? __expf(pv.y - mnew) : 0.f;
    p.z = (pv.z > -1e29f) ? __expf(pv.z - mnew) : 0.f;
    p.w = (pv.w > -1e29f) ? __expf(pv.w - mnew) : 0.f;
    float ps = p.x + p.y + p.z + p.w;
    ps += __shfl_xor(ps, 1);
    ps += __shfl_xor(ps, 2);
    ps += __shfl_xor(ps, 4);
    float sclf = __expf(mold - mnew);  // both -1e30 -> 1, harmless (acc=0,l=0)
    *(float4*)&sc[rr][4 * jj] = p;
    if (jj == 0) {
      mrow[rr] = mnew;
      lrow[rr] = lrow[rr] * sclf + ps;
      srow[rr] = sclf;
    }
    // ---- V chunk -> same LDS buffer (K reads done at last barrier) ----
#pragma unroll
    for (int i = 0; i < 8; ++i) {
      int id = i * 256 + tid;
      int r = id >> 6, c4 = (id & 63) << 2;
      int t = t0 + r;
      float4 vx = make_float4(0.f, 0.f, 0.f, 0.f);
      if (t >= 0 && t < SDIM) vx = *(const float4*)(Vb + (size_t)t * HDIM + c4);
      *(float4*)&kv[r][c4] = vx;
    }
    __syncthreads();
    // ---- PV: thread tile 8 rows x 4 cols ----
#pragma unroll
    for (int r = 0; r < 8; ++r) {
      float s_ = srow[8 * tr + r];
      acc[r][0] *= s_; acc[r][1] *= s_; acc[r][2] *= s_; acc[r][3] *= s_;
    }
    for (int t = 0; t < 32; ++t) {
      float4 vv = *(float4*)&kv[t][4 * td];
#pragma unroll
      for (int r = 0; r < 8; ++r) {
        float p_ = sc[8 * tr + r][t];
        acc[r][0] += p_ * vv.x;
        acc[r][1] += p_ * vv.y;
        acc[r][2] += p_ * vv.z;
        acc[r][3] += p_ * vv.w;
      }
    }
    __syncthreads();
  }
  // ---- epilogue: normalize, sum over this block's 32 rows ----
  float v0 = 0.f, v1 = 0.f, v2 = 0.f, v3 = 0.f;
#pragma unroll
  for (int r = 0; r < 8; ++r) {
    float inv = 1.0f / lrow[8 * tr + r];
    v0 += acc[r][0] * inv;
    v1 += acc[r][1] * inv;
    v2 += acc[r][2] * inv;
    v3 += acc[r][3] * inv;
  }
  *(float4*)&pbuf[tr][4 * td] = make_float4(v0, v1, v2, v3);
  __syncthreads();
  if (tr == 0) {
    float4 a0 = *(float4*)&pbuf[0][4 * td];
    float4 a1 = *(float4*)&pbuf[1][4 * td];
    float4 a2 = *(float4*)&pbuf[2][4 * td];
    float4 a3 = *(float4*)&pbuf[3][4 * td];
    float4 o = make_float4(a0.x + a1.x + a2.x + a3.x, a0.y + a1.y + a2.y + a3.y,
                           a0.z + a1.z + a2.z + a3.z, a0.w + a1.w + a2.w + a3.w);
    *(float4*)(partial + (size_t)blk * HDIM + 4 * td) = o;
  }
}

// ---------------- Kernel 3: deterministic mean reduction ----------------
__global__ void reduce_partials(const float* __restrict__ partial,
                                float* __restrict__ out) {
  const int b = blockIdx.x;
  const int d = threadIdx.x;
  float s = 0.f;
  for (int i = 0; i < 128; ++i)
    s += partial[((size_t)(b * 128 + i)) * HDIM + d];
  out[b * HDIM + d] = s * (1.0f / (float)SDIM);
}

extern "C" void kernel_launch(void* const* d_in, const int* in_sizes, int n_in,
                              void* d_out, int out_size, void* d_ws, size_t ws_size,
                              hipStream_t stream) {
  const float* x  = (const float*)d_in[0];
  const float* Wq = (const float*)d_in[1];
  const float* bq = (const float*)d_in[2];
  const float* Wk = (const float*)d_in[3];
  const float* bk = (const float*)d_in[4];
  const float* Wv = (const float*)d_in[5];
  const float* bv = (const float*)d_in[6];
  float* out = (float*)d_out;

  float* Q = (float*)d_ws;
  float* K = Q + (size_t)NROW * HDIM;
  float* V = K + (size_t)NROW * HDIM;
  float* partial = V + (size_t)NROW * HDIM;  // 512*256 floats

  qkv_proj<<<512, 256, 0, stream>>>(x, Wq, bq, Wk, bk, Wv, bv, Q, K, V);
  local_attn<<<512, 256, 0, stream>>>(Q, K, V, partial);
  reduce_partials<<<4, 256, 0, stream>>>(partial, out);
}

// Round 2
// 218.331 us; speedup vs baseline: 1.2230x; 1.2230x over previous
//
#include <hip/hip_runtime.h>

#define SDIM 4096
#define HDIM 256
#define WIN 128
#define NROW 16384  // B*S

// ---------------- Kernel 1: QKV projection (fp32, VALU) ----------------
// grid (512, 3), block 256. Each block: 32 rows of x (LDS, no pad needed:
// compute reads are wave-uniform broadcasts), ONE matrix (blockIdx.y),
// thread tile = 8 rows x 4 cols, W software-prefetched 4 rows ahead.
__global__ __launch_bounds__(256) void qkv_proj(
    const float* __restrict__ x,
    const float* __restrict__ Wq, const float* __restrict__ bq,
    const float* __restrict__ Wk, const float* __restrict__ bk,
    const float* __restrict__ Wv, const float* __restrict__ bv,
    float* __restrict__ Q, float* __restrict__ K, float* __restrict__ V) {
  __shared__ float xs[32][HDIM];
  const int tid = threadIdx.x;
  const size_t rb = (size_t)blockIdx.x * 32;
  const int m = blockIdx.y;
  const float* __restrict__ W = (m == 0) ? Wq : (m == 1) ? Wk : Wv;
  const float* __restrict__ bb = (m == 0) ? bq : (m == 1) ? bk : bv;
  float* __restrict__ O = (m == 0) ? Q : (m == 1) ? K : V;
#pragma unroll
  for (int i = 0; i < 8; ++i) {
    int id = i * 256 + tid;
    int r = id >> 6, c4 = (id & 63) << 2;
    *(float4*)&xs[r][c4] = *(const float4*)(x + (rb + r) * HDIM + c4);
  }
  __syncthreads();
  const int td = tid & 63, tr = tid >> 6;
  const float* __restrict__ Wp = W + 4 * td;
  float acc[8][4];
#pragma unroll
  for (int r = 0; r < 8; ++r)
#pragma unroll
    for (int c = 0; c < 4; ++c) acc[r][c] = 0.f;

  float4 w0 = *(const float4*)(Wp + 0 * HDIM);
  float4 w1 = *(const float4*)(Wp + 1 * HDIM);
  float4 w2 = *(const float4*)(Wp + 2 * HDIM);
  float4 w3 = *(const float4*)(Wp + 3 * HDIM);

#define QKV_FMA(hh)                                                       \
  do {                                                                    \
    _Pragma("unroll") for (int r = 0; r < 8; ++r) {                       \
      float4 xv = *(float4*)&xs[8 * tr + r][hh];                          \
      acc[r][0] += xv.x * w0.x + xv.y * w1.x + xv.z * w2.x + xv.w * w3.x; \
      acc[r][1] += xv.x * w0.y + xv.y * w1.y + xv.z * w2.y + xv.w * w3.y; \
      acc[r][2] += xv.x * w0.z + xv.y * w1.z + xv.z * w2.z + xv.w * w3.z; \
      acc[r][3] += xv.x * w0.w + xv.y * w1.w + xv.z * w2.w + xv.w * w3.w; \
    }                                                                     \
  } while (0)

#pragma unroll 4
  for (int h = 0; h < HDIM - 4; h += 4) {
    float4 n0 = *(const float4*)(Wp + (size_t)(h + 4) * HDIM);
    float4 n1 = *(const float4*)(Wp + (size_t)(h + 5) * HDIM);
    float4 n2 = *(const float4*)(Wp + (size_t)(h + 6) * HDIM);
    float4 n3 = *(const float4*)(Wp + (size_t)(h + 7) * HDIM);
    QKV_FMA(h);
    w0 = n0; w1 = n1; w2 = n2; w3 = n3;
  }
  QKV_FMA(HDIM - 4);
#undef QKV_FMA

  float4 bias = *(const float4*)(bb + 4 * td);
#pragma unroll
  for (int r = 0; r < 8; ++r) {
    float4 o = make_float4(acc[r][0] + bias.x, acc[r][1] + bias.y,
                           acc[r][2] + bias.z, acc[r][3] + bias.w);
    *(float4*)(O + (rb + 8 * tr + r) * HDIM + 4 * td) = o;
  }
}

// ---------------- Kernel 2: banded attention with online softmax -------
// grid 512 (=B*(S/32)), block 256. QBLK=32, TCHUNK=32, 9 chunks covering
// [s0-128, s0+160). K and V time-share one LDS buffer. Partial column
// sums (context summed over the 32 q-rows) written per block.
__global__ __launch_bounds__(256) void local_attn(
    const float* __restrict__ Q, const float* __restrict__ K,
    const float* __restrict__ V, float* __restrict__ partial) {
  __shared__ float qs[32][HDIM + 4];
  __shared__ float kv[32][HDIM + 4];
  __shared__ float sc[32][36];
  __shared__ float mrow[32], lrow[32], srow[32];
  __shared__ float pbuf[4][HDIM];
  const int tid = threadIdx.x;
  const int blk = blockIdx.x;
  const int b = blk >> 7;
  const int s0 = (blk & 127) << 5;
  const float* Qb = Q + ((size_t)b * SDIM + s0) * HDIM;
  const float* Kb = K + (size_t)b * SDIM * HDIM;
  const float* Vb = V + (size_t)b * SDIM * HDIM;
#pragma unroll
  for (int i = 0; i < 8; ++i) {
    int id = i * 256 + tid;
    int r = id >> 6, c4 = (id & 63) << 2;
    *(float4*)&qs[r][c4] = *(const float4*)(Qb + (size_t)r * HDIM + c4);
  }
  if (tid < 32) { mrow[tid] = -1e30f; lrow[tid] = 0.f; }
  float acc[8][4];
#pragma unroll
  for (int r = 0; r < 8; ++r)
#pragma unroll
    for (int c = 0; c < 4; ++c) acc[r][c] = 0.f;
  const int td = tid & 63, tr = tid >> 6;
  const int tq = tid >> 4, tt = tid & 15;
  const int rr = tid >> 3, jj = tid & 7;
  __syncthreads();
  for (int cidx = 0; cidx < 9; ++cidx) {
    const int t0 = s0 - WIN + cidx * 32;
    if (t0 + 32 <= 0 || t0 >= SDIM) continue;  // uniform skip
    // ---- K chunk -> LDS (guarded) ----
#pragma unroll
    for (int i = 0; i < 8; ++i) {
      int id = i * 256 + tid;
      int r = id >> 6, c4 = (id & 63) << 2;
      int t = t0 + r;
      float4 kx = make_float4(0.f, 0.f, 0.f, 0.f);
      if (t >= 0 && t < SDIM) kx = *(const float4*)(Kb + (size_t)t * HDIM + c4);
      *(float4*)&kv[r][c4] = kx;
    }
    __syncthreads();
    // ---- scores: thread tile rows {tq, tq+16} x cols {tt, tt+16} ----
    float s00 = 0.f, s01 = 0.f, s10 = 0.f, s11 = 0.f;
#pragma unroll 2
    for (int h = 0; h < HDIM; h += 4) {
      float4 q0 = *(float4*)&qs[tq][h];
      float4 q1 = *(float4*)&qs[tq + 16][h];
      float4 k0 = *(float4*)&kv[tt][h];
      float4 k1 = *(float4*)&kv[tt + 16][h];
      s00 += q0.x * k0.x + q0.y * k0.y + q0.z * k0.z + q0.w * k0.w;
      s01 += q0.x * k1.x + q0.y * k1.y + q0.z * k1.z + q0.w * k1.w;
      s10 += q1.x * k0.x + q1.y * k0.y + q1.z * k0.z + q1.w * k0.w;
      s11 += q1.x * k1.x + q1.y * k1.y + q1.z * k1.z + q1.w * k1.w;
    }
    {
      const float rs = 0.0625f;  // 1/sqrt(256)
      int rows[2] = {tq, tq + 16};
      int cols[2] = {tt, tt + 16};
      float vals[2][2] = {{s00, s01}, {s10, s11}};
#pragma unroll
      for (int i = 0; i < 2; ++i)
#pragma unroll
        for (int j = 0; j < 2; ++j) {
          int r = rows[i];
          int t = t0 + cols[j];
          int s = s0 + r;
          bool ok = (t >= 0) && (t < SDIM) && (t >= s - WIN) && (t <= s + WIN);
          sc[r][cols[j]] = ok ? vals[i][j] * rs : -1e30f;
        }
    }
    __syncthreads();
    // ---- online softmax update (8 lanes per row, same wave) ----
    float4 pv = *(float4*)&sc[rr][4 * jj];
    float mc = fmaxf(fmaxf(pv.x, pv.y), fmaxf(pv.z, pv.w));
    mc = fmaxf(mc, __shfl_xor(mc, 1));
    mc = fmaxf(mc, __shfl_xor(mc, 2));
    mc = fmaxf(mc, __shfl_xor(mc, 4));
    float mold = mrow[rr];
    float mnew = fmaxf(mold, mc);
    float4 p;
    p.x = (pv.x > -1e29f) ? __expf(pv.x - mnew) : 0.f;
    p.y = (pv.y > -1e29f) ? __expf(pv.y - mnew) : 0.f;
    p.z = (pv.z > -1e29f) ? __expf(pv.z - mnew) : 0.f;
    p.w = (pv.w > -1e29f) ? __expf(pv.w - mnew) : 0.f;
    float ps = p.x + p.y + p.z + p.w;
    ps += __shfl_xor(ps, 1);
    ps += __shfl_xor(ps, 2);
    ps += __shfl_xor(ps, 4);
    float sclf = __expf(mold - mnew);  // both -1e30 -> 1, harmless (acc=0,l=0)
    *(float4*)&sc[rr][4 * jj] = p;
    if (jj == 0) {
      mrow[rr] = mnew;
      lrow[rr] = lrow[rr] * sclf + ps;
      srow[rr] = sclf;
    }
    // ---- V chunk -> same LDS buffer (K reads done at last barrier) ----
#pragma unroll
    for (int i = 0; i < 8; ++i) {
      int id = i * 256 + tid;
      int r = id >> 6, c4 = (id & 63) << 2;
      int t = t0 + r;
      float4 vx = make_float4(0.f, 0.f, 0.f, 0.f);
      if (t >= 0 && t < SDIM) vx = *(const float4*)(Vb + (size_t)t * HDIM + c4);
      *(float4*)&kv[r][c4] = vx;
    }
    __syncthreads();
    // ---- PV: thread tile 8 rows x 4 cols ----
#pragma unroll
    for (int r = 0; r < 8; ++r) {
      float s_ = srow[8 * tr + r];
      acc[r][0] *= s_; acc[r][1] *= s_; acc[r][2] *= s_; acc[r][3] *= s_;
    }
    for (int t = 0; t < 32; ++t) {
      float4 vv = *(float4*)&kv[t][4 * td];
#pragma unroll
      for (int r = 0; r < 8; ++r) {
        float p_ = sc[8 * tr + r][t];
        acc[r][0] += p_ * vv.x;
        acc[r][1] += p_ * vv.y;
        acc[r][2] += p_ * vv.z;
        acc[r][3] += p_ * vv.w;
      }
    }
    __syncthreads();
  }
  // ---- epilogue: normalize, sum over this block's 32 rows ----
  float v0 = 0.f, v1 = 0.f, v2 = 0.f, v3 = 0.f;
#pragma unroll
  for (int r = 0; r < 8; ++r) {
    float inv = 1.0f / lrow[8 * tr + r];
    v0 += acc[r][0] * inv;
    v1 += acc[r][1] * inv;
    v2 += acc[r][2] * inv;
    v3 += acc[r][3] * inv;
  }
  *(float4*)&pbuf[tr][4 * td] = make_float4(v0, v1, v2, v3);
  __syncthreads();
  if (tr == 0) {
    float4 a0 = *(float4*)&pbuf[0][4 * td];
    float4 a1 = *(float4*)&pbuf[1][4 * td];
    float4 a2 = *(float4*)&pbuf[2][4 * td];
    float4 a3 = *(float4*)&pbuf[3][4 * td];
    float4 o = make_float4(a0.x + a1.x + a2.x + a3.x, a0.y + a1.y + a2.y + a3.y,
                           a0.z + a1.z + a2.z + a3.z, a0.w + a1.w + a2.w + a3.w);
    *(float4*)(partial + (size_t)blk * HDIM + 4 * td) = o;
  }
}

// ---------------- Kernel 3: deterministic mean reduction ----------------
__global__ void reduce_partials(const float* __restrict__ partial,
                                float* __restrict__ out) {
  const int b = blockIdx.x;
  const int d = threadIdx.x;
  float s = 0.f;
  for (int i = 0; i < 128; ++i)
    s += partial[((size_t)(b * 128 + i)) * HDIM + d];
  out[b * HDIM + d] = s * (1.0f / (float)SDIM);
}

extern "C" void kernel_launch(void* const* d_in, const int* in_sizes, int n_in,
                              void* d_out, int out_size, void* d_ws, size_t ws_size,
                              hipStream_t stream) {
  const float* x  = (const float*)d_in[0];
  const float* Wq = (const float*)d_in[1];
  const float* bq = (const float*)d_in[2];
  const float* Wk = (const float*)d_in[3];
  const float* bk = (const float*)d_in[4];
  const float* Wv = (const float*)d_in[5];
  const float* bv = (const float*)d_in[6];
  float* out = (float*)d_out;

  float* Q = (float*)d_ws;
  float* K = Q + (size_t)NROW * HDIM;
  float* V = K + (size_t)NROW * HDIM;
  float* partial = V + (size_t)NROW * HDIM;  // 512*256 floats

  dim3 qgrid(512, 3);
  qkv_proj<<<qgrid, 256, 0, stream>>>(x, Wq, bq, Wk, bk, Wv, bv, Q, K, V);
  local_attn<<<512, 256, 0, stream>>>(Q, K, V, partial);
  reduce_partials<<<4, 256, 0, stream>>>(partial, out);
}

// Round 3
// 132.845 us; speedup vs baseline: 2.0100x; 1.6435x over previous
//
#include <hip/hip_runtime.h>

#define SDIM 4096
#define HDIM 256
#define WIN 128
#define NROW 16384  // B*S
#define QSCALE 0.0625f  // 1/sqrt(256)

typedef __attribute__((ext_vector_type(8))) short bf16x8;
typedef __attribute__((ext_vector_type(4))) float f32x4;

static __device__ __forceinline__ unsigned short f2bf(float f) {
  unsigned int u = __float_as_uint(f);
  unsigned int r = (u + 0x7fffu + ((u >> 16) & 1u)) >> 16;
  return (unsigned short)r;
}

#define MFMA16(a, b, c) __builtin_amdgcn_mfma_f32_16x16x32_bf16((a), (b), (c), 0, 0, 0)

// ---------- Kernel 0: W -> W^T bf16 (Wt[m][n][k] = W_m[k][n]) ----------
__global__ __launch_bounds__(256) void wconv(const float* __restrict__ Wq,
                                             const float* __restrict__ Wk,
                                             const float* __restrict__ Wv,
                                             unsigned short* __restrict__ Wt) {
  const int m = blockIdx.y;
  const float* __restrict__ W = (m == 0) ? Wq : (m == 1) ? Wk : Wv;
  const int idx = (blockIdx.x * 256 + threadIdx.x) * 4;  // flat over W (k*256+n)
  float4 w = *(const float4*)(W + idx);
  const int k = idx >> 8, n = idx & 255;
  unsigned short* o = Wt + (size_t)m * 65536 + k;
  o[(size_t)(n + 0) * HDIM] = f2bf(w.x);
  o[(size_t)(n + 1) * HDIM] = f2bf(w.y);
  o[(size_t)(n + 2) * HDIM] = f2bf(w.z);
  o[(size_t)(n + 3) * HDIM] = f2bf(w.w);
}

// ---------- Kernel 1: QKV projection via bf16 MFMA ----------
// grid 256, block 256 (4 waves, 16 rows each, 64 rows/block).
// Outputs: Qb, Kb row-major bf16 [B*S][H]; Vt transposed bf16 [B][H][S].
__global__ __launch_bounds__(256) void qkv_mfma(
    const float* __restrict__ x, const unsigned short* __restrict__ Wt,
    const float* __restrict__ bq, const float* __restrict__ bk,
    const float* __restrict__ bv, unsigned short* __restrict__ Qb,
    unsigned short* __restrict__ Kb, unsigned short* __restrict__ Vt) {
  __shared__ unsigned short stage[64][HDIM];  // 32 KB
  const int tid = threadIdx.x;
  const int lane = tid & 63, w = tid >> 6;
  const int l15 = lane & 15, g = lane >> 4;
  const size_t rb = (size_t)blockIdx.x * 64;
  // A-frags: x row (rb + 16w + l15), k = 32*kk + 8g + j, fp32->bf16 in reg
  bf16x8 a[8];
  const float* xr = x + (rb + 16 * w + l15) * HDIM + 8 * g;
#pragma unroll
  for (int kk = 0; kk < 8; ++kk) {
    float4 lo = *(const float4*)(xr + 32 * kk);
    float4 hi = *(const float4*)(xr + 32 * kk + 4);
    bf16x8 v;
    v[0] = (short)f2bf(lo.x); v[1] = (short)f2bf(lo.y);
    v[2] = (short)f2bf(lo.z); v[3] = (short)f2bf(lo.w);
    v[4] = (short)f2bf(hi.x); v[5] = (short)f2bf(hi.y);
    v[6] = (short)f2bf(hi.z); v[7] = (short)f2bf(hi.w);
    a[kk] = v;
  }
  const float* biases[3] = {bq, bk, bv};
  for (int m = 0; m < 3; ++m) {
    const unsigned short* Wm = Wt + (size_t)m * 65536;
    const float* bias = biases[m];
#pragma unroll 4
    for (int nt = 0; nt < 16; ++nt) {
      f32x4 acc = {0.f, 0.f, 0.f, 0.f};
      const unsigned short* wp = Wm + (size_t)(nt * 16 + l15) * HDIM + 8 * g;
#pragma unroll
      for (int kk = 0; kk < 8; ++kk) {
        bf16x8 bf = *(const bf16x8*)(wp + 32 * kk);
        acc = MFMA16(a[kk], bf, acc);
      }
      float bn = bias[nt * 16 + l15];
#pragma unroll
      for (int r = 0; r < 4; ++r)
        stage[16 * w + 4 * g + r][nt * 16 + l15] = f2bf(acc[r] + bn);
    }
    __syncthreads();
    if (m < 2) {
      unsigned short* O = (m == 0 ? Qb : Kb) + rb * HDIM;
      const unsigned short* sf = &stage[0][0];
#pragma unroll
      for (int it = 0; it < 8; ++it) {
        int idx = (it * 256 + tid) * 8;
        *(bf16x8*)(O + idx) = *(const bf16x8*)(sf + idx);
      }
    } else {
      // transposed V write: thread d = tid handles column d
      const int d = tid;
      const size_t b = rb >> 12;
      const size_t tloc = rb & 4095;
      unsigned short* o = Vt + ((size_t)b * HDIM + d) * SDIM + tloc;
#pragma unroll
      for (int c = 0; c < 8; ++c) {
        bf16x8 vv;
#pragma unroll
        for (int r = 0; r < 8; ++r) vv[r] = (short)stage[8 * c + r][d];
        *(bf16x8*)(o + 8 * c) = vv;
      }
    }
    __syncthreads();
  }
}

// ---------- Kernel 2: banded attention, all-MFMA, no-max softmax ----------
// grid 1024 (XCD-swizzled), block 64 (1 wave, 16 q-rows). 9 chunks of 32 t.
__global__ __launch_bounds__(64) void attn_mfma(
    const unsigned short* __restrict__ Qb, const unsigned short* __restrict__ Kb,
    const unsigned short* __restrict__ Vt, float* __restrict__ partial) {
  __shared__ unsigned short plds[2][16][40];  // padded P tile, double-buffered
  const int lane = threadIdx.x;
  const int blk = ((int)blockIdx.x & 7) * 128 + ((int)blockIdx.x >> 3);  // XCD swizzle
  const int b = blk >> 8;
  const int s0 = (blk & 255) << 4;
  const int l15 = lane & 15, g = lane >> 4;
  // Q fragments (row = s0 + l15), kept in registers
  bf16x8 qf[8];
  const unsigned short* qr = Qb + ((size_t)b * SDIM + s0 + l15) * HDIM + 8 * g;
#pragma unroll
  for (int kk = 0; kk < 8; ++kk) qf[kk] = *(const bf16x8*)(qr + 32 * kk);
  const unsigned short* Kbb = Kb + (size_t)b * SDIM * HDIM;
  const unsigned short* Vtb = Vt + (size_t)b * HDIM * SDIM;
  f32x4 acc[16];
  const f32x4 zero = {0.f, 0.f, 0.f, 0.f};
#pragma unroll
  for (int i = 0; i < 16; ++i) acc[i] = zero;
  float lacc[4] = {0.f, 0.f, 0.f, 0.f};
  for (int c = 0; c < 9; ++c) {
    const int t0 = s0 - WIN + c * 32;
    if (t0 + 32 <= 0 || t0 >= SDIM) continue;  // wave-uniform skip
    // ---- scores: two 16x16 t-tiles via 8 K-steps each ----
    const int tr0 = min(max(t0 + l15, 0), SDIM - 1);
    const int tr1 = min(max(t0 + 16 + l15, 0), SDIM - 1);
    const unsigned short* k0p = Kbb + (size_t)tr0 * HDIM + 8 * g;
    const unsigned short* k1p = Kbb + (size_t)tr1 * HDIM + 8 * g;
    f32x4 sA = zero, sB = zero;
#pragma unroll
    for (int kk = 0; kk < 8; ++kk) {
      sA = MFMA16(qf[kk], *(const bf16x8*)(k0p + 32 * kk), sA);
      sB = MFMA16(qf[kk], *(const bf16x8*)(k1p + 32 * kk), sB);
    }
    // ---- P = exp(s/16), band-masked; no max subtraction needed ----
    float p0[4], p1[4];
#pragma unroll
    for (int r = 0; r < 4; ++r) {
      int s = s0 + 4 * g + r;
      int ta = t0 + l15, tb = t0 + 16 + l15;
      int da = ta - s, db = tb - s;
      bool okA = (ta >= 0) && (ta < SDIM) && (da <= WIN) && (da >= -WIN);
      bool okB = (tb >= 0) && (tb < SDIM) && (db <= WIN) && (db >= -WIN);
      p0[r] = okA ? __expf(sA[r] * QSCALE) : 0.f;
      p1[r] = okB ? __expf(sB[r] * QSCALE) : 0.f;
    }
    // ---- l partial: column-sum over 32 t (16-lane butterfly) ----
#pragma unroll
    for (int r = 0; r < 4; ++r) {
      float v = p0[r] + p1[r];
      v += __shfl_xor(v, 1);
      v += __shfl_xor(v, 2);
      v += __shfl_xor(v, 4);
      v += __shfl_xor(v, 8);
      lacc[r] += v;
    }
    // ---- P (C-layout) -> LDS -> A-frag ----
    const int bsel = c & 1;
#pragma unroll
    for (int r = 0; r < 4; ++r) {
      plds[bsel][4 * g + r][l15] = f2bf(p0[r]);
      plds[bsel][4 * g + r][16 + l15] = f2bf(p1[r]);
    }
    bf16x8 pa = *(const bf16x8*)(&plds[bsel][l15][8 * g]);
    // ---- PV: 16 d-tiles, B-frags contiguous along t from Vt ----
    const int tv = min(max(t0 + 8 * g, 0), SDIM - 8);
    const unsigned short* vp = Vtb + (size_t)l15 * SDIM + tv;
#pragma unroll
    for (int dt = 0; dt < 16; ++dt) {
      bf16x8 vf = *(const bf16x8*)(vp + (size_t)dt * 16 * SDIM);
      acc[dt] = MFMA16(pa, vf, acc[dt]);
    }
  }
  // ---- epilogue: normalize rows, sum 16 rows, write per-block partial ----
  float inv[4];
#pragma unroll
  for (int r = 0; r < 4; ++r) inv[r] = 1.0f / lacc[r];
#pragma unroll
  for (int dt = 0; dt < 16; ++dt) {
    float s = acc[dt][0] * inv[0] + acc[dt][1] * inv[1] + acc[dt][2] * inv[2] +
              acc[dt][3] * inv[3];
    s += __shfl_xor(s, 16);
    s += __shfl_xor(s, 32);
    if (lane < 16) partial[(size_t)blk * HDIM + dt * 16 + lane] = s;
  }
}

// ---------- Kernel 3: deterministic mean over S ----------
__global__ __launch_bounds__(1024) void reduce_partials(
    const float* __restrict__ partial, float* __restrict__ out) {
  __shared__ float red[4][HDIM];
  const int b = blockIdx.x;
  const int d = threadIdx.x & 255, q = threadIdx.x >> 8;
  float s = 0.f;
  for (int i = q * 64; i < q * 64 + 64; ++i)
    s += partial[((size_t)b * 256 + i) * HDIM + d];
  red[q][d] = s;
  __syncthreads();
  if (q == 0)
    out[b * HDIM + d] =
        (red[0][d] + red[1][d] + red[2][d] + red[3][d]) * (1.0f / (float)SDIM);
}

extern "C" void kernel_launch(void* const* d_in, const int* in_sizes, int n_in,
                              void* d_out, int out_size, void* d_ws, size_t ws_size,
                              hipStream_t stream) {
  const float* x  = (const float*)d_in[0];
  const float* Wq = (const float*)d_in[1];
  const float* bq = (const float*)d_in[2];
  const float* Wk = (const float*)d_in[3];
  const float* bk = (const float*)d_in[4];
  const float* Wv = (const float*)d_in[5];
  const float* bv = (const float*)d_in[6];
  float* out = (float*)d_out;

  unsigned short* Qb = (unsigned short*)d_ws;        // 8 MB
  unsigned short* Kb = Qb + (size_t)NROW * HDIM;     // 8 MB
  unsigned short* Vt = Kb + (size_t)NROW * HDIM;     // 8 MB (transposed)
  unsigned short* Wt = Vt + (size_t)NROW * HDIM;     // 384 KB
  float* partial = (float*)(Wt + 3 * 65536);         // 1 MB

  dim3 wg(64, 3);
  wconv<<<wg, 256, 0, stream>>>(Wq, Wk, Wv, Wt);
  qkv_mfma<<<256, 256, 0, stream>>>(x, Wt, bq, bk, bv, Qb, Kb, Vt);
  attn_mfma<<<1024, 64, 0, stream>>>(Qb, Kb, Vt, partial);
  reduce_partials<<<4, 1024, 0, stream>>>(partial, out);
}

// Round 4
// 116.518 us; speedup vs baseline: 2.2916x; 1.1401x over previous
//
#include <hip/hip_runtime.h>

#define SDIM 4096
#define HDIM 256
#define WIN 128
#define NROW 16384  // B*S
#define QSCALE 0.0625f  // 1/sqrt(256)

typedef __attribute__((ext_vector_type(8))) short bf16x8;
typedef __attribute__((ext_vector_type(4))) float f32x4;

static __device__ __forceinline__ unsigned short f2bf(float f) {
  unsigned int u = __float_as_uint(f);
  unsigned int r = (u + 0x7fffu + ((u >> 16) & 1u)) >> 16;
  return (unsigned short)r;
}

#define MFMA16(a, b, c) __builtin_amdgcn_mfma_f32_16x16x32_bf16((a), (b), (c), 0, 0, 0)

// ---------- Kernel 0: W -> W^T bf16 (Wt[m][n][k] = W_m[k][n]) ----------
__global__ __launch_bounds__(256) void wconv(const float* __restrict__ Wq,
                                             const float* __restrict__ Wk,
                                             const float* __restrict__ Wv,
                                             unsigned short* __restrict__ Wt) {
  const int m = blockIdx.y;
  const float* __restrict__ W = (m == 0) ? Wq : (m == 1) ? Wk : Wv;
  const int idx = (blockIdx.x * 256 + threadIdx.x) * 4;  // flat over W (k*256+n)
  float4 w = *(const float4*)(W + idx);
  const int k = idx >> 8, n = idx & 255;
  unsigned short* o = Wt + (size_t)m * 65536 + k;
  o[(size_t)(n + 0) * HDIM] = f2bf(w.x);
  o[(size_t)(n + 1) * HDIM] = f2bf(w.y);
  o[(size_t)(n + 2) * HDIM] = f2bf(w.z);
  o[(size_t)(n + 3) * HDIM] = f2bf(w.w);
}

// ---------- Kernel 1: QKV projection via bf16 MFMA ----------
// grid (256, 3), block 256 (4 waves, 16 rows each; one matrix per block).
// Outputs: Qb, Kb row-major bf16 [B*S][H]; Vt transposed bf16 [B][H][S].
__global__ __launch_bounds__(256) void qkv_mfma(
    const float* __restrict__ x, const unsigned short* __restrict__ Wt,
    const float* __restrict__ bq, const float* __restrict__ bk,
    const float* __restrict__ bv, unsigned short* __restrict__ Qb,
    unsigned short* __restrict__ Kb, unsigned short* __restrict__ Vt) {
  __shared__ unsigned short stage[64][HDIM];  // 32 KB
  const int tid = threadIdx.x;
  const int lane = tid & 63, w = tid >> 6;
  const int l15 = lane & 15, g = lane >> 4;
  const int m = blockIdx.y;
  const size_t rb = (size_t)blockIdx.x * 64;
  // A-frags: x row (rb + 16w + l15), k = 32*kk + 8g + j, fp32->bf16 in reg
  bf16x8 a[8];
  const float* xr = x + (rb + 16 * w + l15) * HDIM + 8 * g;
#pragma unroll
  for (int kk = 0; kk < 8; ++kk) {
    float4 lo = *(const float4*)(xr + 32 * kk);
    float4 hi = *(const float4*)(xr + 32 * kk + 4);
    bf16x8 v;
    v[0] = (short)f2bf(lo.x); v[1] = (short)f2bf(lo.y);
    v[2] = (short)f2bf(lo.z); v[3] = (short)f2bf(lo.w);
    v[4] = (short)f2bf(hi.x); v[5] = (short)f2bf(hi.y);
    v[6] = (short)f2bf(hi.z); v[7] = (short)f2bf(hi.w);
    a[kk] = v;
  }
  const unsigned short* Wm = Wt + (size_t)m * 65536;
  const float* bias = (m == 0) ? bq : (m == 1) ? bk : bv;
#pragma unroll 4
  for (int nt = 0; nt < 16; ++nt) {
    f32x4 acc = {0.f, 0.f, 0.f, 0.f};
    const unsigned short* wp = Wm + (size_t)(nt * 16 + l15) * HDIM + 8 * g;
#pragma unroll
    for (int kk = 0; kk < 8; ++kk) {
      bf16x8 bf = *(const bf16x8*)(wp + 32 * kk);
      acc = MFMA16(a[kk], bf, acc);
    }
    float bn = bias[nt * 16 + l15];
#pragma unroll
    for (int r = 0; r < 4; ++r)
      stage[16 * w + 4 * g + r][nt * 16 + l15] = f2bf(acc[r] + bn);
  }
  __syncthreads();
  if (m < 2) {
    unsigned short* O = (m == 0 ? Qb : Kb) + rb * HDIM;
    const unsigned short* sf = &stage[0][0];
#pragma unroll
    for (int it = 0; it < 8; ++it) {
      int idx = (it * 256 + tid) * 8;
      *(bf16x8*)(O + idx) = *(const bf16x8*)(sf + idx);
    }
  } else {
    // transposed V write: thread d = tid handles column d
    const int d = tid;
    const size_t b = rb >> 12;
    const size_t tloc = rb & 4095;
    unsigned short* o = Vt + ((size_t)b * HDIM + d) * SDIM + tloc;
#pragma unroll
    for (int c = 0; c < 8; ++c) {
      bf16x8 vv;
#pragma unroll
      for (int r = 0; r < 8; ++r) vv[r] = (short)stage[8 * c + r][d];
      *(bf16x8*)(o + 8 * c) = vv;
    }
  }
}

// ---------- Kernel 2: banded attention, all-MFMA, no-max softmax ----------
// grid 1024 (XCD-swizzled), block 256 = 4 waves. Each block = one 16-row
// q-tile; the 9 t-chunks are split {3,2,2,2} across waves. Per-row (O,l)
// partials are additive (no max subtraction) -> LDS combine, then normalize.
__global__ __launch_bounds__(256) void attn_mfma(
    const unsigned short* __restrict__ Qb, const unsigned short* __restrict__ Kb,
    const unsigned short* __restrict__ Vt, float* __restrict__ partial) {
  __shared__ float obuf[16][260];   // 16.6 KB combined context
  __shared__ float lbuf[16];
  __shared__ float linv[16];
  __shared__ unsigned short plds[4][2][16][40];  // per-wave P tiles, 10.2 KB
  const int tid = threadIdx.x;
  const int lane = tid & 63, w = tid >> 6;
  const int bid = blockIdx.x;
  const int blk = (bid & 7) * 128 + (bid >> 3);  // bijective XCD swizzle (1024=8*128)
  const int b = blk >> 8;
  const int s0 = (blk & 255) << 4;
  const int l15 = lane & 15, g = lane >> 4;
  // Q fragments (row = s0 + l15), kept in registers
  bf16x8 qf[8];
  const unsigned short* qr = Qb + ((size_t)b * SDIM + s0 + l15) * HDIM + 8 * g;
#pragma unroll
  for (int kk = 0; kk < 8; ++kk) qf[kk] = *(const bf16x8*)(qr + 32 * kk);
  const unsigned short* Kbb = Kb + (size_t)b * SDIM * HDIM;
  const unsigned short* Vtb = Vt + (size_t)b * HDIM * SDIM;
  f32x4 acc[16];
  const f32x4 zero = {0.f, 0.f, 0.f, 0.f};
#pragma unroll
  for (int i = 0; i < 16; ++i) acc[i] = zero;
  float lacc[4] = {0.f, 0.f, 0.f, 0.f};
  const int cb = (w == 0) ? 0 : 1 + 2 * w;  // {0,3,5,7}
  const int ce = 3 + 2 * w;                 // {3,5,7,9}
  for (int c = cb; c < ce; ++c) {
    const int t0 = s0 - WIN + c * 32;
    if (t0 + 32 <= 0 || t0 >= SDIM) continue;  // wave-uniform skip
    // ---- scores: two 16x16 t-tiles via 8 K-steps each ----
    const int tr0 = min(max(t0 + l15, 0), SDIM - 1);
    const int tr1 = min(max(t0 + 16 + l15, 0), SDIM - 1);
    const unsigned short* k0p = Kbb + (size_t)tr0 * HDIM + 8 * g;
    const unsigned short* k1p = Kbb + (size_t)tr1 * HDIM + 8 * g;
    f32x4 sA = zero, sB = zero;
#pragma unroll
    for (int kk = 0; kk < 8; ++kk) {
      sA = MFMA16(qf[kk], *(const bf16x8*)(k0p + 32 * kk), sA);
      sB = MFMA16(qf[kk], *(const bf16x8*)(k1p + 32 * kk), sB);
    }
    // ---- P = exp(s/16), band-masked; no max subtraction needed ----
    float p0[4], p1[4];
#pragma unroll
    for (int r = 0; r < 4; ++r) {
      int s = s0 + 4 * g + r;
      int ta = t0 + l15, tb = t0 + 16 + l15;
      int da = ta - s, db = tb - s;
      bool okA = (ta >= 0) && (ta < SDIM) && (da <= WIN) && (da >= -WIN);
      bool okB = (tb >= 0) && (tb < SDIM) && (db <= WIN) && (db >= -WIN);
      p0[r] = okA ? __expf(sA[r] * QSCALE) : 0.f;
      p1[r] = okB ? __expf(sB[r] * QSCALE) : 0.f;
    }
    // ---- l partial: column-sum over 32 t (16-lane butterfly) ----
#pragma unroll
    for (int r = 0; r < 4; ++r) {
      float v = p0[r] + p1[r];
      v += __shfl_xor(v, 1);
      v += __shfl_xor(v, 2);
      v += __shfl_xor(v, 4);
      v += __shfl_xor(v, 8);
      lacc[r] += v;
    }
    // ---- P (C-layout) -> LDS -> A-frag ----
    const int bsel = c & 1;
#pragma unroll
    for (int r = 0; r < 4; ++r) {
      plds[w][bsel][4 * g + r][l15] = f2bf(p0[r]);
      plds[w][bsel][4 * g + r][16 + l15] = f2bf(p1[r]);
    }
    bf16x8 pa = *(const bf16x8*)(&plds[w][bsel][l15][8 * g]);
    // ---- PV: 16 d-tiles, B-frags contiguous along t from Vt ----
    const int tv = min(max(t0 + 8 * g, 0), SDIM - 8);
    const unsigned short* vp = Vtb + (size_t)l15 * SDIM + tv;
#pragma unroll
    for (int dt = 0; dt < 16; ++dt) {
      bf16x8 vf = *(const bf16x8*)(vp + (size_t)dt * 16 * SDIM);
      acc[dt] = MFMA16(pa, vf, acc[dt]);
    }
  }
  // ---- combine the 4 waves' (O,l) partials in LDS ----
  if (w == 0) {
#pragma unroll
    for (int dt = 0; dt < 16; ++dt)
#pragma unroll
      for (int r = 0; r < 4; ++r) obuf[4 * g + r][dt * 16 + l15] = acc[dt][r];
    if (l15 == 0)
#pragma unroll
      for (int r = 0; r < 4; ++r) lbuf[4 * g + r] = lacc[r];
  }
  __syncthreads();
#pragma unroll
  for (int wv = 1; wv < 4; ++wv) {
    if (w == wv) {
#pragma unroll
      for (int dt = 0; dt < 16; ++dt)
#pragma unroll
        for (int r = 0; r < 4; ++r) obuf[4 * g + r][dt * 16 + l15] += acc[dt][r];
      if (l15 == 0)
#pragma unroll
        for (int r = 0; r < 4; ++r) lbuf[4 * g + r] += lacc[r];
    }
    __syncthreads();
  }
  if (tid < 16) linv[tid] = 1.0f / lbuf[tid];
  __syncthreads();
  // ---- normalize rows, sum the 16 rows, write per-block partial ----
  float s = 0.f;
#pragma unroll
  for (int row = 0; row < 16; ++row) s += obuf[row][tid] * linv[row];
  partial[(size_t)blk * HDIM + tid] = s;
}

// ---------- Kernel 3: deterministic mean over S ----------
__global__ __launch_bounds__(1024) void reduce_partials(
    const float* __restrict__ partial, float* __restrict__ out) {
  __shared__ float red[4][HDIM];
  const int b = blockIdx.x;
  const int d = threadIdx.x & 255, q = threadIdx.x >> 8;
  float s = 0.f;
  for (int i = q * 64; i < q * 64 + 64; ++i)
    s += partial[((size_t)b * 256 + i) * HDIM + d];
  red[q][d] = s;
  __syncthreads();
  if (q == 0)
    out[b * HDIM + d] =
        (red[0][d] + red[1][d] + red[2][d] + red[3][d]) * (1.0f / (float)SDIM);
}

extern "C" void kernel_launch(void* const* d_in, const int* in_sizes, int n_in,
                              void* d_out, int out_size, void* d_ws, size_t ws_size,
                              hipStream_t stream) {
  const float* x  = (const float*)d_in[0];
  const float* Wq = (const float*)d_in[1];
  const float* bq = (const float*)d_in[2];
  const float* Wk = (const float*)d_in[3];
  const float* bk = (const float*)d_in[4];
  const float* Wv = (const float*)d_in[5];
  const float* bv = (const float*)d_in[6];
  float* out = (float*)d_out;

  unsigned short* Qb = (unsigned short*)d_ws;        // 8 MB
  unsigned short* Kb = Qb + (size_t)NROW * HDIM;     // 8 MB
  unsigned short* Vt = Kb + (size_t)NROW * HDIM;     // 8 MB (transposed)
  unsigned short* Wt = Vt + (size_t)NROW * HDIM;     // 384 KB
  float* partial = (float*)(Wt + 3 * 65536);         // 1 MB

  dim3 wg(64, 3);
  wconv<<<wg, 256, 0, stream>>>(Wq, Wk, Wv, Wt);
  dim3 qgrid(256, 3);
  qkv_mfma<<<qgrid, 256, 0, stream>>>(x, Wt, bq, bk, bv, Qb, Kb, Vt);
  attn_mfma<<<1024, 256, 0, stream>>>(Qb, Kb, Vt, partial);
  reduce_partials<<<4, 1024, 0, stream>>>(partial, out);
}

// Round 5
// 73.681 us; speedup vs baseline: 3.6239x; 1.5814x over previous
//
#include <hip/hip_runtime.h>

#define SDIM 4096
#define HDIM 256
#define WIN 128
#define NROW 16384  // B*S
#define QSCALE 0.0625f  // 1/sqrt(256)

typedef __attribute__((ext_vector_type(8))) short bf16x8;
typedef __attribute__((ext_vector_type(4))) float f32x4;

static __device__ __forceinline__ unsigned short f2bf(float f) {
  unsigned int u = __float_as_uint(f);
  unsigned int r = (u + 0x7fffu + ((u >> 16) & 1u)) >> 16;
  return (unsigned short)r;
}

#define MFMA16(a, b, c) __builtin_amdgcn_mfma_f32_16x16x32_bf16((a), (b), (c), 0, 0, 0)

// Frag-packed layout: block of 512 shorts per (tile16, kk):
//   pack[tile][kk][lane][j] = M[16*tile + (lane&15)][32*kk + 8*(lane>>4) + j]
// so a wave's A/B-frag load is `base + lane*8` = coalesced 1KB.

// ---------- Kernel A: x fp32 -> frag-packed bf16 ----------
__global__ __launch_bounds__(256) void xconv(const float* __restrict__ x,
                                             unsigned short* __restrict__ xp) {
  const int tid = threadIdx.x, lane = tid & 63, w = tid >> 6;
  const int l15 = lane & 15, g = lane >> 4;
  const int rt = blockIdx.x;  // 16-row tile, 0..1023
  const float* xr = x + ((size_t)rt * 16 + l15) * HDIM + 8 * g;
  unsigned short* op = xp + (size_t)rt * 4096;
#pragma unroll
  for (int half = 0; half < 2; ++half) {
    int kk = w * 2 + half;
    float4 lo = *(const float4*)(xr + 32 * kk);
    float4 hi = *(const float4*)(xr + 32 * kk + 4);
    bf16x8 v;
    v[0] = (short)f2bf(lo.x); v[1] = (short)f2bf(lo.y);
    v[2] = (short)f2bf(lo.z); v[3] = (short)f2bf(lo.w);
    v[4] = (short)f2bf(hi.x); v[5] = (short)f2bf(hi.y);
    v[6] = (short)f2bf(hi.z); v[7] = (short)f2bf(hi.w);
    *(bf16x8*)(op + (size_t)(kk * 64 + lane) * 8) = v;
  }
}

// ---------- Kernel B: W -> frag-packed bf16 W^T ----------
__global__ __launch_bounds__(256) void wconv(const float* __restrict__ Wq,
                                             const float* __restrict__ Wk,
                                             const float* __restrict__ Wv,
                                             unsigned short* __restrict__ Wp) {
  const int m = blockIdx.y, nt = blockIdx.x;
  const float* __restrict__ W = (m == 0) ? Wq : (m == 1) ? Wk : Wv;
  const int tid = threadIdx.x, lane = tid & 63, w = tid >> 6;
  const int l15 = lane & 15, g = lane >> 4;
#pragma unroll
  for (int half = 0; half < 2; ++half) {
    int kk = w * 2 + half;
    bf16x8 v;
#pragma unroll
    for (int j = 0; j < 8; ++j)
      v[j] = (short)f2bf(W[(size_t)(32 * kk + 8 * g + j) * HDIM + 16 * nt + l15]);
    *(bf16x8*)(Wp + ((size_t)(m * 16 + nt) * 8 + kk) * 512 + (size_t)lane * 8) = v;
  }
}

// ---------- Kernel 1: QKV projection, all loads coalesced frag-packed ----------
// grid (256, 3), block 256 (4 waves; wave w = 16-row tile rt=4bx+w; m per blockIdx.y).
// Writes Qp/Kp in frag-packed layout; Vp in PV-packed layout
//   Vp[tg][dt][gg][l15][j] = V[16*tg + 8*gg + j][16*dt + l15]
__global__ __launch_bounds__(256) void qkv_mfma(
    const unsigned short* __restrict__ xp, const unsigned short* __restrict__ Wp,
    const float* __restrict__ bq, const float* __restrict__ bk,
    const float* __restrict__ bv, unsigned short* __restrict__ Qp,
    unsigned short* __restrict__ Kp, unsigned short* __restrict__ Vp) {
  __shared__ unsigned short stage[64][264];  // padded: +8 shorts/row
  const int tid = threadIdx.x;
  const int lane = tid & 63, w = tid >> 6;
  const int l15 = lane & 15, g = lane >> 4;
  const int m = blockIdx.y;
  const int rt = blockIdx.x * 4 + w;  // 16-row tile
  bf16x8 a[8];
  const unsigned short* ap = xp + (size_t)rt * 4096 + (size_t)lane * 8;
#pragma unroll
  for (int kk = 0; kk < 8; ++kk) a[kk] = *(const bf16x8*)(ap + kk * 512);
  const unsigned short* Wm = Wp + (size_t)m * 65536;
  const float* bias = (m == 0) ? bq : (m == 1) ? bk : bv;
#pragma unroll 2
  for (int nt = 0; nt < 16; ++nt) {
    f32x4 acc = {0.f, 0.f, 0.f, 0.f};
    const unsigned short* wp_ = Wm + (size_t)nt * 4096 + (size_t)lane * 8;
#pragma unroll
    for (int kk = 0; kk < 8; ++kk)
      acc = MFMA16(a[kk], *(const bf16x8*)(wp_ + kk * 512), acc);
    float bn = bias[nt * 16 + l15];
#pragma unroll
    for (int r = 0; r < 4; ++r)
      stage[16 * w + 4 * g + r][16 * nt + l15] = f2bf(acc[r] + bn);
  }
  __syncthreads();
  const size_t rb = (size_t)blockIdx.x * 64;
  const int bidx = (int)(rb >> 12);
  const int tgbase = (int)((rb >> 4) & 255);
  if (m < 2) {
    unsigned short* O = (m == 0 ? Qp : Kp) + ((size_t)bidx * 256 + tgbase) * 4096;
#pragma unroll
    for (int it = 0; it < 8; ++it) {
      int u = it * 4 + w;  // 0..31 = (tgl, kk)
      int kk = u & 7, tgl = u >> 3;
      bf16x8 vv = *(const bf16x8*)&stage[16 * tgl + l15][32 * kk + 8 * g];
      *(bf16x8*)(O + ((size_t)tgl * 8 + kk) * 512 + (size_t)lane * 8) = vv;
    }
  } else {
    unsigned short* O = Vp + ((size_t)bidx * 256 + tgbase) * 4096;
#pragma unroll
    for (int it = 0; it < 8; ++it) {
      int u = it * 256 + tid;  // 0..2047 enumerates [tgl][dt][gg][l15]
      int l15o = u & 15, gg = (u >> 4) & 1, dt = (u >> 5) & 15, tgl = u >> 9;
      bf16x8 vv;
#pragma unroll
      for (int j = 0; j < 8; ++j)
        vv[j] = (short)stage[16 * tgl + 8 * gg + j][16 * dt + l15o];
      *(bf16x8*)(O + (size_t)u * 8) = vv;
    }
  }
}

// ---------- Kernel 2: banded attention, all-MFMA, coalesced packed loads ----------
// grid 1024 (XCD-swizzled), block 256 = 4 waves; chunks {3,2,2,2} split by wave.
__global__ __launch_bounds__(256) void attn_mfma(
    const unsigned short* __restrict__ Qp, const unsigned short* __restrict__ Kp,
    const unsigned short* __restrict__ Vp, float* __restrict__ partial) {
  __shared__ float obuf[16][260];
  __shared__ float lbuf[16];
  __shared__ float linv[16];
  __shared__ unsigned short plds[4][2][16][40];
  const int tid = threadIdx.x;
  const int lane = tid & 63, w = tid >> 6;
  const int bid = blockIdx.x;
  const int blk = (bid & 7) * 128 + (bid >> 3);  // bijective XCD swizzle
  const int b = blk >> 8;
  const int qt = blk & 255;
  const int s0 = qt << 4;
  const int l15 = lane & 15, g = lane >> 4;
  bf16x8 qf[8];
  const unsigned short* qp_ = Qp + ((size_t)b * 256 + qt) * 4096 + (size_t)lane * 8;
#pragma unroll
  for (int kk = 0; kk < 8; ++kk) qf[kk] = *(const bf16x8*)(qp_ + kk * 512);
  const unsigned short* Kb = Kp + (size_t)b * 1048576;
  const unsigned short* Vb = Vp + (size_t)b * 1048576;
  f32x4 acc[16];
  const f32x4 zero = {0.f, 0.f, 0.f, 0.f};
#pragma unroll
  for (int i = 0; i < 16; ++i) acc[i] = zero;
  float lacc[4] = {0.f, 0.f, 0.f, 0.f};
  const int cb = (w == 0) ? 0 : 1 + 2 * w;  // {0,3,5,7}
  const int ce = 3 + 2 * w;                 // {3,5,7,9}
  for (int c = cb; c < ce; ++c) {
    const int t0 = s0 - WIN + c * 32;
    if (t0 + 32 <= 0 || t0 >= SDIM) continue;  // wave-uniform skip
    const int tg = t0 >> 4;  // signed 16-row tile index
    const int tga = min(max(tg, 0), 255);
    const int tgb = min(max(tg + 1, 0), 255);
    const unsigned short* kap = Kb + (size_t)tga * 4096 + (size_t)lane * 8;
    const unsigned short* kbp = Kb + (size_t)tgb * 4096 + (size_t)lane * 8;
    f32x4 sA = zero, sB = zero;
#pragma unroll
    for (int kk = 0; kk < 8; ++kk) {
      sA = MFMA16(qf[kk], *(const bf16x8*)(kap + kk * 512), sA);
      sB = MFMA16(qf[kk], *(const bf16x8*)(kbp + kk * 512), sB);
    }
    // ---- P = exp(s/16), band-masked (no max subtraction needed) ----
    float p0[4], p1[4];
#pragma unroll
    for (int r = 0; r < 4; ++r) {
      int s = s0 + 4 * g + r;
      int ta = t0 + l15, tb = t0 + 16 + l15;
      int da = ta - s, db = tb - s;
      bool okA = (ta >= 0) && (ta < SDIM) && (da <= WIN) && (da >= -WIN);
      bool okB = (tb >= 0) && (tb < SDIM) && (db <= WIN) && (db >= -WIN);
      p0[r] = okA ? __expf(sA[r] * QSCALE) : 0.f;
      p1[r] = okB ? __expf(sB[r] * QSCALE) : 0.f;
    }
#pragma unroll
    for (int r = 0; r < 4; ++r) {
      float v = p0[r] + p1[r];
      v += __shfl_xor(v, 1);
      v += __shfl_xor(v, 2);
      v += __shfl_xor(v, 4);
      v += __shfl_xor(v, 8);
      lacc[r] += v;
    }
    // ---- P (C-layout) -> LDS -> A-frag ----
    const int bsel = c & 1;
#pragma unroll
    for (int r = 0; r < 4; ++r) {
      plds[w][bsel][4 * g + r][l15] = f2bf(p0[r]);
      plds[w][bsel][4 * g + r][16 + l15] = f2bf(p1[r]);
    }
    bf16x8 pa = *(const bf16x8*)(&plds[w][bsel][l15][8 * g]);
    // ---- PV: 16 d-tiles from PV-packed V (coalesced, dt stride 256) ----
    const int tgv = min(max(tg + (g >> 1), 0), 255);
    const unsigned short* vp_ =
        Vb + (size_t)tgv * 4096 + (size_t)(g & 1) * 128 + (size_t)l15 * 8;
#pragma unroll
    for (int dt = 0; dt < 16; ++dt) {
      bf16x8 vf = *(const bf16x8*)(vp_ + dt * 256);
      acc[dt] = MFMA16(pa, vf, acc[dt]);
    }
  }
  // ---- combine the 4 waves' (O,l) partials in LDS ----
  if (w == 0) {
#pragma unroll
    for (int dt = 0; dt < 16; ++dt)
#pragma unroll
      for (int r = 0; r < 4; ++r) obuf[4 * g + r][dt * 16 + l15] = acc[dt][r];
    if (l15 == 0)
#pragma unroll
      for (int r = 0; r < 4; ++r) lbuf[4 * g + r] = lacc[r];
  }
  __syncthreads();
#pragma unroll
  for (int wv = 1; wv < 4; ++wv) {
    if (w == wv) {
#pragma unroll
      for (int dt = 0; dt < 16; ++dt)
#pragma unroll
        for (int r = 0; r < 4; ++r) obuf[4 * g + r][dt * 16 + l15] += acc[dt][r];
      if (l15 == 0)
#pragma unroll
        for (int r = 0; r < 4; ++r) lbuf[4 * g + r] += lacc[r];
    }
    __syncthreads();
  }
  if (tid < 16) linv[tid] = 1.0f / lbuf[tid];
  __syncthreads();
  float s = 0.f;
#pragma unroll
  for (int row = 0; row < 16; ++row) s += obuf[row][tid] * linv[row];
  partial[(size_t)blk * HDIM + tid] = s;
}

// ---------- Kernel 3: deterministic mean over S ----------
__global__ __launch_bounds__(1024) void reduce_partials(
    const float* __restrict__ partial, float* __restrict__ out) {
  __shared__ float red[4][HDIM];
  const int b = blockIdx.x;
  const int d = threadIdx.x & 255, q = threadIdx.x >> 8;
  float s = 0.f;
  for (int i = q * 64; i < q * 64 + 64; ++i)
    s += partial[((size_t)b * 256 + i) * HDIM + d];
  red[q][d] = s;
  __syncthreads();
  if (q == 0)
    out[b * HDIM + d] =
        (red[0][d] + red[1][d] + red[2][d] + red[3][d]) * (1.0f / (float)SDIM);
}

extern "C" void kernel_launch(void* const* d_in, const int* in_sizes, int n_in,
                              void* d_out, int out_size, void* d_ws, size_t ws_size,
                              hipStream_t stream) {
  const float* x  = (const float*)d_in[0];
  const float* Wq = (const float*)d_in[1];
  const float* bq = (const float*)d_in[2];
  const float* Wk = (const float*)d_in[3];
  const float* bk = (const float*)d_in[4];
  const float* Wv = (const float*)d_in[5];
  const float* bv = (const float*)d_in[6];
  float* out = (float*)d_out;

  unsigned short* xp = (unsigned short*)d_ws;        // 8.4 MB packed x
  unsigned short* Qp = xp + (size_t)NROW * HDIM;     // 8.4 MB
  unsigned short* Kp = Qp + (size_t)NROW * HDIM;     // 8.4 MB
  unsigned short* Vp = Kp + (size_t)NROW * HDIM;     // 8.4 MB
  unsigned short* Wp = Vp + (size_t)NROW * HDIM;     // 384 KB
  float* partial = (float*)(Wp + 3 * 65536);         // 1 MB

  xconv<<<1024, 256, 0, stream>>>(x, xp);
  dim3 wg(16, 3);
  wconv<<<wg, 256, 0, stream>>>(Wq, Wk, Wv, Wp);
  dim3 qgrid(256, 3);
  qkv_mfma<<<qgrid, 256, 0, stream>>>(xp, Wp, bq, bk, bv, Qp, Kp, Vp);
  attn_mfma<<<1024, 256, 0, stream>>>(Qp, Kp, Vp, partial);
  reduce_partials<<<4, 1024, 0, stream>>>(partial, out);
}

// Round 7
// 72.633 us; speedup vs baseline: 3.6762x; 1.0144x over previous
//
#include <hip/hip_runtime.h>

#define SDIM 4096
#define HDIM 256
#define WIN 128
#define NROW 16384  // B*S
#define QSCALE 0.0625f  // 1/sqrt(256)

typedef __attribute__((ext_vector_type(8))) short bf16x8;
typedef __attribute__((ext_vector_type(4))) float f32x4;

static __device__ __forceinline__ unsigned short f2bf(float f) {
  unsigned int u = __float_as_uint(f);
  return (unsigned short)((u + 0x7fffu + ((u >> 16) & 1u)) >> 16);
}

#define MFMA16(a, b, c) __builtin_amdgcn_mfma_f32_16x16x32_bf16((a), (b), (c), 0, 0, 0)

// Frag-packed layout (per 16-row tile, per kk): pack[tile][kk][lane][j] =
//   M[16*tile + (lane&15)][32*kk + 8*(lane>>4) + j]  -> wave load = base+lane*8.
// V PV-packed: Vp[tile][dt][gg][l15][j] = V[16*tile + 8*gg + j][16*dt + l15].

// ---------- Kernel 0: W -> frag-packed bf16 W^T ----------
__global__ __launch_bounds__(256) void wconv(const float* __restrict__ Wq,
                                             const float* __restrict__ Wk,
                                             const float* __restrict__ Wv,
                                             unsigned short* __restrict__ Wp) {
  const int m = blockIdx.y, nt = blockIdx.x;
  const float* __restrict__ W = (m == 0) ? Wq : (m == 1) ? Wk : Wv;
  const int tid = threadIdx.x, lane = tid & 63, w = tid >> 6;
  const int l15 = lane & 15, g = lane >> 4;
#pragma unroll
  for (int half = 0; half < 2; ++half) {
    int kk = w * 2 + half;
    bf16x8 v;
#pragma unroll
    for (int j = 0; j < 8; ++j)
      v[j] = (short)f2bf(W[(size_t)(32 * kk + 8 * g + j) * HDIM + 16 * nt + l15]);
    *(bf16x8*)(Wp + ((size_t)(m * 16 + nt) * 8 + kk) * 512 + (size_t)lane * 8) = v;
  }
}

// ---------- Kernel 1: QKV projection; x staged fp32->bf16 in-kernel ----------
// grid (256, 3), block 256 (4 waves; wave = one 16-row tile; m per blockIdx.y).
__global__ __launch_bounds__(256) void qkv_mfma(
    const float* __restrict__ x, const unsigned short* __restrict__ Wp,
    const float* __restrict__ bq, const float* __restrict__ bk,
    const float* __restrict__ bv, unsigned short* __restrict__ Qp,
    unsigned short* __restrict__ Kp, unsigned short* __restrict__ Vp) {
  __shared__ unsigned short st[64][264];  // x-stage, then out-stage (33.8 KB)
  const int tid = threadIdx.x;
  const int lane = tid & 63, w = tid >> 6;
  const int l15 = lane & 15, g = lane >> 4;
  const int m = blockIdx.y;
  const size_t rb = (size_t)blockIdx.x * 64;
  // ---- stage 64 rows of x, fully coalesced fp32 read, bf16 convert ----
#pragma unroll
  for (int it = 0; it < 16; ++it) {
    int u = it * 256 + tid;  // float4 index
    int r = u >> 6, c4 = (u & 63) << 2;
    float4 f = *(const float4*)(x + (rb + r) * HDIM + c4);
    st[r][c4 + 0] = f2bf(f.x);
    st[r][c4 + 1] = f2bf(f.y);
    st[r][c4 + 2] = f2bf(f.z);
    st[r][c4 + 3] = f2bf(f.w);
  }
  __syncthreads();
  bf16x8 a[8];
#pragma unroll
  for (int kk = 0; kk < 8; ++kk)
    a[kk] = *(const bf16x8*)&st[16 * w + l15][32 * kk + 8 * g];
  __syncthreads();  // all waves done reading x-stage; st becomes out-stage
  const unsigned short* Wm = Wp + (size_t)m * 65536;
  const float* bias = (m == 0) ? bq : (m == 1) ? bk : bv;
#pragma unroll 2
  for (int ntp = 0; ntp < 8; ++ntp) {
    int nt0 = ntp * 2;
    const unsigned short* w0p = Wm + (size_t)nt0 * 4096 + (size_t)lane * 8;
    const unsigned short* w1p = w0p + 4096;
    f32x4 a0 = {0.f, 0.f, 0.f, 0.f}, a1 = {0.f, 0.f, 0.f, 0.f};
#pragma unroll
    for (int kk = 0; kk < 8; ++kk) {
      a0 = MFMA16(a[kk], *(const bf16x8*)(w0p + kk * 512), a0);
      a1 = MFMA16(a[kk], *(const bf16x8*)(w1p + kk * 512), a1);
    }
    float b0 = bias[nt0 * 16 + l15], b1 = bias[nt0 * 16 + 16 + l15];
#pragma unroll
    for (int r = 0; r < 4; ++r) {
      st[16 * w + 4 * g + r][nt0 * 16 + l15] = f2bf(a0[r] + b0);
      st[16 * w + 4 * g + r][nt0 * 16 + 16 + l15] = f2bf(a1[r] + b1);
    }
  }
  __syncthreads();
  const int bidx = (int)(rb >> 12);
  const int tgbase = (int)((rb >> 4) & 255);
  if (m < 2) {
    unsigned short* O = (m == 0 ? Qp : Kp) + ((size_t)bidx * 256 + tgbase) * 4096;
#pragma unroll
    for (int it = 0; it < 8; ++it) {
      int u = it * 4 + w;  // (tgl, kk)
      int kk = u & 7, tgl = u >> 3;
      bf16x8 vv = *(const bf16x8*)&st[16 * tgl + l15][32 * kk + 8 * g];
      *(bf16x8*)(O + ((size_t)tgl * 8 + kk) * 512 + (size_t)lane * 8) = vv;
    }
  } else {
    unsigned short* O = Vp + ((size_t)bidx * 256 + tgbase) * 4096;
#pragma unroll
    for (int it = 0; it < 8; ++it) {
      int u = it * 256 + tid;  // [tgl][dt][gg][l15]
      int lc = u & 15, gg = (u >> 4) & 1, dt = (u >> 5) & 15, tgl = u >> 9;
      bf16x8 vv;
#pragma unroll
      for (int j = 0; j < 8; ++j)
        vv[j] = (short)st[16 * tgl + 8 * gg + j][16 * dt + lc];
      *(bf16x8*)(O + (size_t)u * 8) = vv;
    }
  }
}

// ---------- Kernel 2: banded attention, all-MFMA, coalesced packed loads ----------
// grid 1024 (XCD-swizzled), block 256 = 4 waves; chunks {3,2,2,2} split by wave.
__global__ __launch_bounds__(256) void attn_mfma(
    const unsigned short* __restrict__ Qp, const unsigned short* __restrict__ Kp,
    const unsigned short* __restrict__ Vp, float* __restrict__ partial) {
  __shared__ float obuf[16][260];
  __shared__ float lbuf[16];
  __shared__ float linv[16];
  __shared__ unsigned short plds[4][2][16][40];
  const int tid = threadIdx.x;
  const int lane = tid & 63, w = tid >> 6;
  const int bid = blockIdx.x;
  const int blk = (bid & 7) * 128 + (bid >> 3);  // bijective XCD swizzle
  const int b = blk >> 8;
  const int qt = blk & 255;
  const int s0 = qt << 4;
  const int l15 = lane & 15, g = lane >> 4;
  bf16x8 qf[8];
  const unsigned short* qp_ = Qp + ((size_t)b * 256 + qt) * 4096 + (size_t)lane * 8;
#pragma unroll
  for (int kk = 0; kk < 8; ++kk) qf[kk] = *(const bf16x8*)(qp_ + kk * 512);
  const unsigned short* Kb = Kp + (size_t)b * 1048576;
  const unsigned short* Vb = Vp + (size_t)b * 1048576;
  f32x4 acc[16];
  const f32x4 zero = {0.f, 0.f, 0.f, 0.f};
#pragma unroll
  for (int i = 0; i < 16; ++i) acc[i] = zero;
  float lacc[4] = {0.f, 0.f, 0.f, 0.f};
  const int cb = (w == 0) ? 0 : 1 + 2 * w;  // {0,3,5,7}
  const int ce = 3 + 2 * w;                 // {3,5,7,9}
  for (int c = cb; c < ce; ++c) {
    const int t0 = s0 - WIN + c * 32;
    if (t0 + 32 <= 0 || t0 >= SDIM) continue;  // wave-uniform skip
    const int tg = t0 >> 4;
    const int tga = min(max(tg, 0), 255);
    const int tgb = min(max(tg + 1, 0), 255);
    const unsigned short* kap = Kb + (size_t)tga * 4096 + (size_t)lane * 8;
    const unsigned short* kbp = Kb + (size_t)tgb * 4096 + (size_t)lane * 8;
    f32x4 sA = zero, sB = zero;
#pragma unroll
    for (int kk = 0; kk < 8; ++kk) {
      sA = MFMA16(qf[kk], *(const bf16x8*)(kap + kk * 512), sA);
      sB = MFMA16(qf[kk], *(const bf16x8*)(kbp + kk * 512), sB);
    }
    float p0[4], p1[4];
#pragma unroll
    for (int r = 0; r < 4; ++r) {
      int s = s0 + 4 * g + r;
      int ta = t0 + l15, tb = t0 + 16 + l15;
      bool okA = (ta >= 0) && (ta < SDIM) && (ta - s <= WIN) && (ta - s >= -WIN);
      bool okB = (tb >= 0) && (tb < SDIM) && (tb - s <= WIN) && (tb - s >= -WIN);
      p0[r] = okA ? __expf(sA[r] * QSCALE) : 0.f;
      p1[r] = okB ? __expf(sB[r] * QSCALE) : 0.f;
    }
#pragma unroll
    for (int r = 0; r < 4; ++r) {
      float v = p0[r] + p1[r];
      v += __shfl_xor(v, 1);
      v += __shfl_xor(v, 2);
      v += __shfl_xor(v, 4);
      v += __shfl_xor(v, 8);
      lacc[r] += v;
    }
    const int bsel = c & 1;
#pragma unroll
    for (int r = 0; r < 4; ++r) {
      plds[w][bsel][4 * g + r][l15] = f2bf(p0[r]);
      plds[w][bsel][4 * g + r][16 + l15] = f2bf(p1[r]);
    }
    bf16x8 pa = *(const bf16x8*)&plds[w][bsel][l15][8 * g];
    const int tgv = min(max(tg + (g >> 1), 0), 255);
    const unsigned short* vp_ =
        Vb + (size_t)tgv * 4096 + (size_t)(g & 1) * 128 + (size_t)l15 * 8;
#pragma unroll
    for (int dt = 0; dt < 16; ++dt)
      acc[dt] = MFMA16(pa, *(const bf16x8*)(vp_ + dt * 256), acc[dt]);
  }
  // ---- combine the 4 waves' (O,l) partials in LDS ----
  if (w == 0) {
#pragma unroll
    for (int dt = 0; dt < 16; ++dt)
#pragma unroll
      for (int r = 0; r < 4; ++r) obuf[4 * g + r][dt * 16 + l15] = acc[dt][r];
    if (l15 == 0)
#pragma unroll
      for (int r = 0; r < 4; ++r) lbuf[4 * g + r] = lacc[r];
  }
  __syncthreads();
#pragma unroll
  for (int wv = 1; wv < 4; ++wv) {
    if (w == wv) {
#pragma unroll
      for (int dt = 0; dt < 16; ++dt)
#pragma unroll
        for (int r = 0; r < 4; ++r) obuf[4 * g + r][dt * 16 + l15] += acc[dt][r];
      if (l15 == 0)
#pragma unroll
        for (int r = 0; r < 4; ++r) lbuf[4 * g + r] += lacc[r];
    }
    __syncthreads();
  }
  if (tid < 16) linv[tid] = 1.0f / lbuf[tid];
  __syncthreads();
  float s = 0.f;
#pragma unroll
  for (int row = 0; row < 16; ++row) s += obuf[row][tid] * linv[row];
  partial[(size_t)blk * HDIM + tid] = s;
}

// ---------- Kernel 3: deterministic mean over S ----------
__global__ __launch_bounds__(1024) void reduce_partials(
    const float* __restrict__ partial, float* __restrict__ out) {
  __shared__ float red[4][HDIM];
  const int b = blockIdx.x;
  const int d = threadIdx.x & 255, q = threadIdx.x >> 8;
  float s = 0.f;
  for (int i = q * 64; i < q * 64 + 64; ++i)
    s += partial[((size_t)b * 256 + i) * HDIM + d];
  red[q][d] = s;
  __syncthreads();
  if (q == 0)
    out[b * HDIM + d] =
        (red[0][d] + red[1][d] + red[2][d] + red[3][d]) * (1.0f / (float)SDIM);
}

extern "C" void kernel_launch(void* const* d_in, const int* in_sizes, int n_in,
                              void* d_out, int out_size, void* d_ws, size_t ws_size,
                              hipStream_t stream) {
  const float* x  = (const float*)d_in[0];
  const float* Wq = (const float*)d_in[1];
  const float* bq = (const float*)d_in[2];
  const float* Wk = (const float*)d_in[3];
  const float* bk = (const float*)d_in[4];
  const float* Wv = (const float*)d_in[5];
  const float* bv = (const float*)d_in[6];
  float* out = (float*)d_out;

  unsigned short* Wp = (unsigned short*)d_ws;           // 384 KB
  unsigned short* Qp = Wp + 3 * 65536;                  // 8.4 MB
  unsigned short* Kp = Qp + (size_t)NROW * HDIM;        // 8.4 MB
  unsigned short* Vp = Kp + (size_t)NROW * HDIM;        // 8.4 MB
  float* partial = (float*)(Vp + (size_t)NROW * HDIM);  // 1 MB

  dim3 wg(16, 3);
  wconv<<<wg, 256, 0, stream>>>(Wq, Wk, Wv, Wp);
  dim3 qgrid(256, 3);
  qkv_mfma<<<qgrid, 256, 0, stream>>>(x, Wp, bq, bk, bv, Qp, Kp, Vp);
  attn_mfma<<<1024, 256, 0, stream>>>(Qp, Kp, Vp, partial);
  reduce_partials<<<4, 1024, 0, stream>>>(partial, out);
}